// Round 1
// baseline (922.316 us; speedup 1.0000x reference)
//
#include <hip/hip_runtime.h>
#include <hip/hip_bf16.h>
#include <math.h>

#define TT 8192
#define HH 2048
#define DD 2048
#define EE 8

typedef short bf16x8 __attribute__((ext_vector_type(8)));
typedef float f32x4 __attribute__((ext_vector_type(4)));

__device__ __forceinline__ ushort f2bf(float f){
  unsigned u = __float_as_uint(f);
  u += 0x7fffu + ((u>>16)&1u);
  return (ushort)(u>>16);
}

// async global->LDS, 16B per lane; LDS dest = wave-uniform base + lane*16
#define GLOAD16(SRC,DST) \
  __builtin_amdgcn_global_load_lds((const __attribute__((address_space(1))) void*)(SRC), \
                                   (__attribute__((address_space(3))) void*)(DST), 16, 0, 0)

// ---------------- fp32 -> bf16 bulk convert ----------------
__global__ __launch_bounds__(256) void cvt_kernel(const float* __restrict__ src,
                                                  ushort* __restrict__ dst, size_t n){
  size_t i = ((size_t)blockIdx.x*256 + threadIdx.x)*8;
  size_t stride = (size_t)gridDim.x*256*8;
  for (; i < n; i += stride){
    float4 a = *(const float4*)(src+i);
    float4 b = *(const float4*)(src+i+4);
    uint4 v;
    v.x = (unsigned)f2bf(a.x) | ((unsigned)f2bf(a.y)<<16);
    v.y = (unsigned)f2bf(a.z) | ((unsigned)f2bf(a.w)<<16);
    v.z = (unsigned)f2bf(b.x) | ((unsigned)f2bf(b.y)<<16);
    v.w = (unsigned)f2bf(b.z) | ((unsigned)f2bf(b.w)<<16);
    *(uint4*)(dst+i) = v;
  }
}

// ---------------- router: fp64 rmsnorm+logits, top-2, build expert lists ----------------
__global__ __launch_bounds__(256) void router_kernel(
    const float* __restrict__ x, const float* __restrict__ rscale,
    const float* __restrict__ pes, const float* __restrict__ rw,
    ushort* __restrict__ x16, int* __restrict__ cnt,
    int* __restrict__ tok, float* __restrict__ wgt)
{
  int t = blockIdx.x;
  int tid = threadIdx.x;
  const float4* xr  = (const float4*)(x + (size_t)t*HH);
  const float4* rs4 = (const float4*)rscale;
  float4 xa = xr[tid], xb = xr[tid+256];
  float4 sa = rs4[tid], sb = rs4[tid+256];
  double xd[8] = {xa.x,xa.y,xa.z,xa.w,xb.x,xb.y,xb.z,xb.w};
  double sd[8] = {sa.x,sa.y,sa.z,sa.w,sb.x,sb.y,sb.z,sb.w};
  double acc[9];
  double ss = 0.0;
  #pragma unroll
  for (int j=0;j<8;j++) ss += xd[j]*xd[j];
  acc[8] = ss;
  double xs[8];
  #pragma unroll
  for (int j=0;j<8;j++) xs[j] = xd[j]*sd[j];
  #pragma unroll
  for (int e=0;e<EE;e++){
    const float4* w4 = (const float4*)(rw + (size_t)e*HH);
    float4 wa = w4[tid], wb = w4[tid+256];
    double wd[8] = {wa.x,wa.y,wa.z,wa.w,wb.x,wb.y,wb.z,wb.w};
    double d = 0.0;
    #pragma unroll
    for (int j=0;j<8;j++) d += xs[j]*wd[j];
    acc[e] = d;
  }
  // write x as bf16 for the FFN GEMMs
  uint2 pa, pb;
  pa.x = (unsigned)f2bf(xa.x) | ((unsigned)f2bf(xa.y)<<16);
  pa.y = (unsigned)f2bf(xa.z) | ((unsigned)f2bf(xa.w)<<16);
  pb.x = (unsigned)f2bf(xb.x) | ((unsigned)f2bf(xb.y)<<16);
  pb.y = (unsigned)f2bf(xb.z) | ((unsigned)f2bf(xb.w)<<16);
  uint2* xo = (uint2*)(x16 + (size_t)t*HH);
  xo[tid] = pa; xo[tid+256] = pb;

  __shared__ double red[9*256];
  #pragma unroll
  for (int j=0;j<9;j++) red[j*256+tid] = acc[j];
  __syncthreads();
  for (int s=128;s>0;s>>=1){
    if (tid < s){
      #pragma unroll
      for (int j=0;j<9;j++) red[j*256+tid] += red[j*256+tid+s];
    }
    __syncthreads();
  }
  if (tid==0){
    double mean = red[8*256] / (double)HH;
    double rms  = 1.0 / sqrt(mean + 1e-6);
    double sc   = rms / sqrt((double)HH);
    double l[EE];
    #pragma unroll
    for (int e=0;e<EE;e++) l[e] = red[e*256]*sc;
    int i0 = 0;
    #pragma unroll
    for (int e=1;e<EE;e++) if (l[e] > l[i0]) i0 = e;   // ties -> lowest index (matches lax.top_k)
    int i1 = -1;
    #pragma unroll
    for (int e=0;e<EE;e++){ if (e==i0) continue; if (i1 < 0 || l[e] > l[i1]) i1 = e; }
    double p1 = exp(l[i1]-l[i0]);
    double s  = 1.0 + p1;                 // softmax denom cancels in the top-2 renorm
    float w0 = (float)((1.0/s) * (double)pes[i0]);
    float w1 = (float)((p1 /s) * (double)pes[i1]);
    int pos0 = atomicAdd(&cnt[i0],1);
    tok[i0*TT+pos0] = t; wgt[i0*TT+pos0] = w0;
    int pos1 = atomicAdd(&cnt[i1],1);
    tok[i1*TT+pos1] = t; wgt[i1*TT+pos1] = w1;
  }
}

// ---------------- exclusive scan of expert counts ----------------
__global__ void scan_kernel(const int* __restrict__ cnt, int* __restrict__ off){
  if (threadIdx.x==0 && blockIdx.x==0){
    int a = 0;
    for (int e=0;e<EE;e++){ off[e]=a; a+=cnt[e]; }
    off[EE]=a;   // == 2*TT
  }
}

// ---------------- GEMM1: gathered x rows -> fused gate/up + GELU, h (bf16) ----------------
// block = 128 rows x (64 gate cols + 64 up cols), BK=32, 4 waves (2x2), mfma 16x16x32
__global__ __launch_bounds__(256,2) void ffn1_kernel(
    const ushort* __restrict__ x16, const ushort* __restrict__ w13,
    const int* __restrict__ cnt, const int* __restrict__ off,
    const int* __restrict__ tok, ushort* __restrict__ hbuf)
{
  int e  = blockIdx.z;
  int ce = cnt[e];
  int m0 = blockIdx.y*128;
  if (m0 >= ce) return;
  int n0 = blockIdx.x*64;
  __shared__ alignas(16) ushort lds_a[128*32];
  __shared__ alignas(16) ushort lds_b[128*32];   // rows 0..63 gate, 64..127 up
  int tid = threadIdx.x, wid = tid>>6, lane = tid&63;
  int wm = wid>>1, wn = wid&1;

  // staging: wave w stages tile rows [w*32, w*32+32); lane -> row (lane>>2), 16B chunk (lane&3)
  int sr = wid*32 + (lane>>2);
  int sc = lane&3;
  int ra = min(m0+sr,    ce-1);
  int rb = min(m0+sr+16, ce-1);
  const ushort* srcA0 = x16 + (size_t)tok[e*TT+ra]*HH + sc*8;
  const ushort* srcA1 = x16 + (size_t)tok[e*TT+rb]*HH + sc*8;
  int br0 = sr, br1 = sr+16;
  size_t wbase = (size_t)e*2*DD*HH;
  const ushort* srcB0 = w13 + wbase + (size_t)((br0<64)?(n0+br0):(DD+n0+br0-64))*HH + sc*8;
  const ushort* srcB1 = w13 + wbase + (size_t)((br1<64)?(n0+br1):(DD+n0+br1-64))*HH + sc*8;
  ushort* dA0 = &lds_a[(wid*32   )*32];
  ushort* dA1 = &lds_a[(wid*32+16)*32];
  ushort* dB0 = &lds_b[(wid*32   )*32];
  ushort* dB1 = &lds_b[(wid*32+16)*32];

  f32x4 accg[4][2], accu[4][2];
  #pragma unroll
  for (int i=0;i<4;i++)
    #pragma unroll
    for (int j=0;j<2;j++){ accg[i][j] = {0.f,0.f,0.f,0.f}; accu[i][j] = {0.f,0.f,0.f,0.f}; }

  int frow = lane&15, fk = (lane>>4)*8;

  for (int k0=0;k0<HH;k0+=32){
    GLOAD16(srcA0 + k0, dA0);
    GLOAD16(srcA1 + k0, dA1);
    GLOAD16(srcB0 + k0, dB0);
    GLOAD16(srcB1 + k0, dB1);
    __syncthreads();     // drains vmcnt then barrier: tiles ready
    bf16x8 a[4], bg[2], bu[2];
    #pragma unroll
    for (int i=0;i<4;i++)
      a[i] = *(const bf16x8*)&lds_a[(wm*64 + i*16 + frow)*32 + fk];
    #pragma unroll
    for (int j=0;j<2;j++){
      bg[j] = *(const bf16x8*)&lds_b[(     wn*32 + j*16 + frow)*32 + fk];
      bu[j] = *(const bf16x8*)&lds_b[(64 + wn*32 + j*16 + frow)*32 + fk];
    }
    #pragma unroll
    for (int i=0;i<4;i++)
      #pragma unroll
      for (int j=0;j<2;j++){
        accg[i][j] = __builtin_amdgcn_mfma_f32_16x16x32_bf16(a[i], bg[j], accg[i][j],0,0,0);
        accu[i][j] = __builtin_amdgcn_mfma_f32_16x16x32_bf16(a[i], bu[j], accu[i][j],0,0,0);
      }
    __syncthreads();     // compute done before next-stage overwrite
  }

  int oe = off[e];
  #pragma unroll
  for (int i=0;i<4;i++){
    int rbase = wm*64 + i*16 + (lane>>4)*4;
    #pragma unroll
    for (int q=0;q<4;q++){
      int gm = m0 + rbase + q;
      if (gm < ce){
        size_t hrow = (size_t)(oe + gm)*DD;
        #pragma unroll
        for (int j=0;j<2;j++){
          int col = n0 + wn*32 + j*16 + frow;
          float g = accg[i][j][q], u = accu[i][j][q];
          float tt = 0.7978845608028654f*(g + 0.044715f*g*g*g);
          float hv = 0.5f*g*(1.f+tanhf(tt))*u;    // tanh-approx GELU * up
          hbuf[hrow + col] = f2bf(hv);
        }
      }
    }
  }
}

// ---------------- GEMM2: h @ down^T, weighted atomic scatter-add into out ----------------
// block = 128 rows x 128 cols, BK=32, 4 waves (2x2)
__global__ __launch_bounds__(256,2) void ffn2_kernel(
    const ushort* __restrict__ hbuf, const ushort* __restrict__ w2,
    const int* __restrict__ cnt, const int* __restrict__ off,
    const int* __restrict__ tok, const float* __restrict__ wgt,
    float* __restrict__ out)
{
  int e  = blockIdx.z;
  int ce = cnt[e];
  int m0 = blockIdx.y*128;
  if (m0 >= ce) return;
  int n0 = blockIdx.x*128;
  __shared__ alignas(16) ushort lds_a[128*32];
  __shared__ alignas(16) ushort lds_b[128*32];
  int tid = threadIdx.x, wid = tid>>6, lane = tid&63;
  int wm = wid>>1, wn = wid&1;
  int oe = off[e];

  int sr = wid*32 + (lane>>2);
  int sc = lane&3;
  int ra = oe + min(m0+sr,    ce-1);
  int rb = oe + min(m0+sr+16, ce-1);
  const ushort* srcA0 = hbuf + (size_t)ra*DD + sc*8;
  const ushort* srcA1 = hbuf + (size_t)rb*DD + sc*8;
  size_t wbase = (size_t)e*HH*DD;
  const ushort* srcB0 = w2 + wbase + (size_t)(n0 + sr   )*DD + sc*8;
  const ushort* srcB1 = w2 + wbase + (size_t)(n0 + sr+16)*DD + sc*8;
  ushort* dA0 = &lds_a[(wid*32   )*32];
  ushort* dA1 = &lds_a[(wid*32+16)*32];
  ushort* dB0 = &lds_b[(wid*32   )*32];
  ushort* dB1 = &lds_b[(wid*32+16)*32];

  f32x4 acc[4][4];
  #pragma unroll
  for (int i=0;i<4;i++)
    #pragma unroll
    for (int j=0;j<4;j++) acc[i][j] = {0.f,0.f,0.f,0.f};

  int frow = lane&15, fk = (lane>>4)*8;

  for (int k0=0;k0<DD;k0+=32){
    GLOAD16(srcA0 + k0, dA0);
    GLOAD16(srcA1 + k0, dA1);
    GLOAD16(srcB0 + k0, dB0);
    GLOAD16(srcB1 + k0, dB1);
    __syncthreads();
    bf16x8 a[4], b[4];
    #pragma unroll
    for (int i=0;i<4;i++)
      a[i] = *(const bf16x8*)&lds_a[(wm*64 + i*16 + frow)*32 + fk];
    #pragma unroll
    for (int j=0;j<4;j++)
      b[j] = *(const bf16x8*)&lds_b[(wn*64 + j*16 + frow)*32 + fk];
    #pragma unroll
    for (int i=0;i<4;i++)
      #pragma unroll
      for (int j=0;j<4;j++)
        acc[i][j] = __builtin_amdgcn_mfma_f32_16x16x32_bf16(a[i], b[j], acc[i][j],0,0,0);
    __syncthreads();
  }

  #pragma unroll
  for (int i=0;i<4;i++){
    int rbase = wm*64 + i*16 + (lane>>4)*4;
    #pragma unroll
    for (int q=0;q<4;q++){
      int gm = m0 + rbase + q;
      if (gm < ce){
        int   tk = tok[e*TT+gm];
        float w  = wgt[e*TT+gm];
        float* orow = out + (size_t)tk*HH;
        #pragma unroll
        for (int j=0;j<4;j++){
          int col = n0 + wn*64 + j*16 + frow;
          atomicAdd(orow + col, w*acc[i][j][q]);   // exactly 2 adds per element: commutative -> deterministic
        }
      }
    }
  }
}

extern "C" void kernel_launch(void* const* d_in, const int* in_sizes, int n_in,
                              void* d_out, int out_size, void* d_ws, size_t ws_size,
                              hipStream_t stream)
{
  const float* x    = (const float*)d_in[0];
  const float* rsc  = (const float*)d_in[1];
  const float* pes  = (const float*)d_in[2];
  const float* rw   = (const float*)d_in[3];
  const float* w13f = (const float*)d_in[4];
  const float* w2f  = (const float*)d_in[5];
  float* out = (float*)d_out;

  char* ws = (char*)d_ws;
  size_t o_x16 = 0;
  size_t o_w13 = o_x16 + (size_t)TT*HH*2;          // x16:  32 MiB
  size_t o_w2  = o_w13 + (size_t)EE*2*DD*HH*2;     // w13: 128 MiB
  size_t o_h   = o_w2  + (size_t)EE*HH*DD*2;       // w2:   64 MiB
  size_t o_cnt = o_h   + (size_t)2*TT*DD*2;        // h:    64 MiB
  size_t o_off = o_cnt + 128;
  size_t o_tok = o_off + 128;
  size_t o_wgt = o_tok + (size_t)EE*TT*4;
  size_t need  = o_wgt + (size_t)EE*TT*4;          // ~302.5 MB total

  hipMemsetAsync(d_out, 0, (size_t)TT*HH*sizeof(float), stream);
  if (ws_size < need) return;   // insufficient scratch -> leaves zeros (visible failure)

  ushort* x16 = (ushort*)(ws + o_x16);
  ushort* w13 = (ushort*)(ws + o_w13);
  ushort* w2  = (ushort*)(ws + o_w2);
  ushort* hbuf= (ushort*)(ws + o_h);
  int*   cnt  = (int*)(ws + o_cnt);
  int*   off  = (int*)(ws + o_off);
  int*   tok  = (int*)(ws + o_tok);
  float* wgt  = (float*)(ws + o_wgt);

  hipMemsetAsync(cnt, 0, EE*sizeof(int), stream);
  cvt_kernel<<<4096,256,0,stream>>>(w13f, w13, (size_t)EE*2*DD*HH);
  cvt_kernel<<<2048,256,0,stream>>>(w2f,  w2,  (size_t)EE*HH*DD);
  router_kernel<<<TT,256,0,stream>>>(x, rsc, pes, rw, x16, cnt, tok, wgt);
  scan_kernel<<<1,64,0,stream>>>(cnt, off);
  dim3 g1(DD/64, TT/128, EE);
  ffn1_kernel<<<g1,256,0,stream>>>(x16, w13, cnt, off, tok, hbuf);
  dim3 g2(HH/128, TT/128, EE);
  ffn2_kernel<<<g2,256,0,stream>>>(hbuf, w2, cnt, off, tok, wgt, out);
}

// Round 2
// 880.935 us; speedup vs baseline: 1.0470x; 1.0470x over previous
//
#include <hip/hip_runtime.h>
#include <hip/hip_bf16.h>
#include <math.h>

#define TT 8192
#define HH 2048
#define DD 2048
#define EE 8
#define NT 32   // K/64 for both GEMMs (K=2048)

typedef short bf16x8 __attribute__((ext_vector_type(8)));
typedef float f32x4 __attribute__((ext_vector_type(4)));

__device__ __forceinline__ ushort f2bf(float f){
  unsigned u = __float_as_uint(f);
  u += 0x7fffu + ((u>>16)&1u);
  return (ushort)(u>>16);
}

#define GLOAD16(SRC,DST) \
  __builtin_amdgcn_global_load_lds((const __attribute__((address_space(1))) void*)(SRC), \
                                   (__attribute__((address_space(3))) void*)(DST), 16, 0, 0)

#define SBAR __builtin_amdgcn_sched_barrier(0)
#define BARR __builtin_amdgcn_s_barrier()
#define WLG  asm volatile("s_waitcnt lgkmcnt(0)" ::: "memory")
#define WVM6 asm volatile("s_waitcnt vmcnt(6)" ::: "memory")
#define PRI(x) __builtin_amdgcn_s_setprio(x)

// ---------------- fp32 -> bf16 bulk convert ----------------
__global__ __launch_bounds__(256) void cvt_kernel(const float* __restrict__ src,
                                                  ushort* __restrict__ dst, size_t n){
  size_t i = ((size_t)blockIdx.x*256 + threadIdx.x)*8;
  size_t stride = (size_t)gridDim.x*256*8;
  for (; i < n; i += stride){
    float4 a = *(const float4*)(src+i);
    float4 b = *(const float4*)(src+i+4);
    uint4 v;
    v.x = (unsigned)f2bf(a.x) | ((unsigned)f2bf(a.y)<<16);
    v.y = (unsigned)f2bf(a.z) | ((unsigned)f2bf(a.w)<<16);
    v.z = (unsigned)f2bf(b.x) | ((unsigned)f2bf(b.y)<<16);
    v.w = (unsigned)f2bf(b.z) | ((unsigned)f2bf(b.w)<<16);
    *(uint4*)(dst+i) = v;
  }
}

// ---------------- router: fp64 rmsnorm+logits, top-2, expert lists ----------------
__global__ __launch_bounds__(256) void router_kernel(
    const float* __restrict__ x, const float* __restrict__ rscale,
    const float* __restrict__ pes, const float* __restrict__ rw,
    ushort* __restrict__ x16, int* __restrict__ cnt,
    int* __restrict__ tok, float* __restrict__ wgt)
{
  int t = blockIdx.x;
  int tid = threadIdx.x;
  const float4* xr  = (const float4*)(x + (size_t)t*HH);
  const float4* rs4 = (const float4*)rscale;
  float4 xa = xr[tid], xb = xr[tid+256];
  float4 sa = rs4[tid], sb = rs4[tid+256];
  double xd[8] = {xa.x,xa.y,xa.z,xa.w,xb.x,xb.y,xb.z,xb.w};
  double sd[8] = {sa.x,sa.y,sa.z,sa.w,sb.x,sb.y,sb.z,sb.w};
  double acc[9];
  double ss = 0.0;
  #pragma unroll
  for (int j=0;j<8;j++) ss += xd[j]*xd[j];
  acc[8] = ss;
  double xs[8];
  #pragma unroll
  for (int j=0;j<8;j++) xs[j] = xd[j]*sd[j];
  #pragma unroll
  for (int e=0;e<EE;e++){
    const float4* w4 = (const float4*)(rw + (size_t)e*HH);
    float4 wa = w4[tid], wb = w4[tid+256];
    double wd[8] = {wa.x,wa.y,wa.z,wa.w,wb.x,wb.y,wb.z,wb.w};
    double d = 0.0;
    #pragma unroll
    for (int j=0;j<8;j++) d += xs[j]*wd[j];
    acc[e] = d;
  }
  uint2 pa, pb;
  pa.x = (unsigned)f2bf(xa.x) | ((unsigned)f2bf(xa.y)<<16);
  pa.y = (unsigned)f2bf(xa.z) | ((unsigned)f2bf(xa.w)<<16);
  pb.x = (unsigned)f2bf(xb.x) | ((unsigned)f2bf(xb.y)<<16);
  pb.y = (unsigned)f2bf(xb.z) | ((unsigned)f2bf(xb.w)<<16);
  uint2* xo = (uint2*)(x16 + (size_t)t*HH);
  xo[tid] = pa; xo[tid+256] = pb;

  __shared__ double red[9*256];
  #pragma unroll
  for (int j=0;j<9;j++) red[j*256+tid] = acc[j];
  __syncthreads();
  for (int s=128;s>0;s>>=1){
    if (tid < s){
      #pragma unroll
      for (int j=0;j<9;j++) red[j*256+tid] += red[j*256+tid+s];
    }
    __syncthreads();
  }
  if (tid==0){
    double mean = red[8*256] / (double)HH;
    double rms  = 1.0 / sqrt(mean + 1e-6);
    double sc   = rms / sqrt((double)HH);
    double l[EE];
    #pragma unroll
    for (int e=0;e<EE;e++) l[e] = red[e*256]*sc;
    int i0 = 0;
    #pragma unroll
    for (int e=1;e<EE;e++) if (l[e] > l[i0]) i0 = e;
    int i1 = -1;
    #pragma unroll
    for (int e=0;e<EE;e++){ if (e==i0) continue; if (i1 < 0 || l[e] > l[i1]) i1 = e; }
    double p1 = exp(l[i1]-l[i0]);
    double s  = 1.0 + p1;
    float w0 = (float)((1.0/s) * (double)pes[i0]);
    float w1 = (float)((p1 /s) * (double)pes[i1]);
    int pos0 = atomicAdd(&cnt[i0],1);
    tok[i0*TT+pos0] = t; wgt[i0*TT+pos0] = w0;
    int pos1 = atomicAdd(&cnt[i1],1);
    tok[i1*TT+pos1] = t; wgt[i1*TT+pos1] = w1;
  }
}

__global__ void scan_kernel(const int* __restrict__ cnt, int* __restrict__ off){
  if (threadIdx.x==0 && blockIdx.x==0){
    int a = 0;
    for (int e=0;e<EE;e++){ off[e]=a; a+=cnt[e]; }
    off[EE]=a;
  }
}

// ---- shared 8-phase machinery (macros; all indices compile-time) ----
// LDS tile: [256 rows][64 cols] bf16 per operand, double buffered. 16B chunk
// swizzle: slot c holds global chunk c ^ (row&7); reads apply same XOR.
#define STA(bb,h,t) do{ \
    GLOAD16(pA[2*(h)  ] + (size_t)(t)*64, &ldsA[bb][(h)*8192        + wid*512]); \
    GLOAD16(pA[2*(h)+1] + (size_t)(t)*64, &ldsA[bb][(h)*8192 + 4096 + wid*512]); }while(0)
#define STB(bb,h,t) do{ \
    GLOAD16(pB[2*(h)  ] + (size_t)(t)*64, &ldsB[bb][(h)*8192        + wid*512]); \
    GLOAD16(pB[2*(h)+1] + (size_t)(t)*64, &ldsB[bb][(h)*8192 + 4096 + wid*512]); }while(0)

#define RD_A(h) do{ _Pragma("unroll") \
  for (int mf=0;mf<4;mf++){ int row=(h)*128 + wm*64 + mf*16 + frow; \
    a[mf][0] = *(const bf16x8*)&As[row*64 + c0]; \
    a[mf][1] = *(const bf16x8*)&As[row*64 + c1]; } }while(0)
#define RD_B(h,bb_) do{ _Pragma("unroll") \
  for (int nf=0;nf<2;nf++){ int row=(h)*128 + wn*32 + nf*16 + frow; \
    bb_[nf][0] = *(const bf16x8*)&Bs[row*64 + c0]; \
    bb_[nf][1] = *(const bf16x8*)&Bs[row*64 + c1]; } }while(0)

#define MMQ(mo,no,bb_) do{ _Pragma("unroll") \
  for (int mf=0;mf<4;mf++){ _Pragma("unroll") \
    for (int nf=0;nf<2;nf++){ \
      acc[(mo)+mf][(no)+nf] = __builtin_amdgcn_mfma_f32_16x16x32_bf16(a[mf][0], bb_[nf][0], acc[(mo)+mf][(no)+nf],0,0,0); \
      acc[(mo)+mf][(no)+nf] = __builtin_amdgcn_mfma_f32_16x16x32_bf16(a[mf][1], bb_[nf][1], acc[(mo)+mf][(no)+nf],0,0,0); } } }while(0)

// K-loop: 4 phases/K-tile. Stage slots: P1->A1(t+1), P2->A0(t+2), P3->B0(t+2),
// P4->B1(t+2); vmcnt(6) at P4 leaves exactly those 3 half-tiles in flight and
// guarantees all of tile t+1 resident. Every stage targets a region whose last
// read finished >=1 barrier earlier.
#define KLOOP for (int t=0;t<NT;t++){ \
    int cur=t&1, nxt=cur^1; \
    const ushort* As=&ldsA[cur][0]; const ushort* Bs=&ldsB[cur][0]; \
    RD_A(0); RD_B(0,b0); \
    if (t+1<NT) STA(nxt,1,t+1); \
    SBAR; BARR; WLG; SBAR; PRI(1); MMQ(0,0,b0); PRI(0); SBAR; BARR; SBAR; \
    RD_B(1,b1); \
    if (t+2<NT) STA(cur,0,t+2); \
    SBAR; BARR; WLG; SBAR; PRI(1); MMQ(0,2,b1); PRI(0); SBAR; BARR; SBAR; \
    RD_A(1); \
    if (t+2<NT) STB(cur,0,t+2); \
    SBAR; BARR; WLG; SBAR; PRI(1); MMQ(4,0,b0); PRI(0); SBAR; BARR; SBAR; \
    if (t+2<NT) STB(cur,1,t+2); \
    SBAR; BARR; SBAR; PRI(1); MMQ(4,2,b1); PRI(0); SBAR; WVM6; BARR; SBAR; \
  }

#define PROLOGUE \
  STA(0,0,0); STB(0,0,0); STB(0,1,0); STA(0,1,0); \
  STA(1,0,1); STB(1,0,1); STB(1,1,1); \
  SBAR; WVM6; BARR; SBAR;

// ---------------- GEMM1: 256 rows x 128 h-cols, gate/up interleaved in B ----------------
// B-tile row g: pair p=g>>5, mat=(g>>4)&1 (0=gate,1=up), h-col = n0+p*16+(g&15).
// Per wave: nf0/nf2 = gate, nf1/nf3 = up for the same h-cols -> in-register GELU combine.
__global__ __launch_bounds__(512,2) void ffn1_kernel(
    const ushort* __restrict__ x16, const ushort* __restrict__ w13,
    const int* __restrict__ cnt, const int* __restrict__ off,
    const int* __restrict__ tok, ushort* __restrict__ hbuf)
{
  int e  = blockIdx.z;
  int ce = cnt[e];
  int m0 = blockIdx.y<<8;
  if (m0 >= ce) return;
  int n0 = blockIdx.x<<7;

  __shared__ ushort ldsA[2][256*64];
  __shared__ ushort ldsB[2][256*64];

  int tid = threadIdx.x, wid = tid>>6, lane = tid&63;
  int wm = wid>>2, wn = wid&3;
  int frow = lane&15, klane = lane>>4;
  int c0 = ((klane  ) ^ (frow&7))<<3;
  int c1 = ((klane+4) ^ (frow&7))<<3;

  int r   = wid*8 + (lane>>3);             // staging row base (0..63)
  int csw = ((lane&7) ^ (lane>>3))<<3;     // inverse-swizzled source chunk

  const ushort* pA[4]; const ushort* pB[4];
  int oe = off[e];
  #pragma unroll
  for (int k=0;k<4;k++){
    int R  = k*64 + r;
    int ar = min(m0+R, ce-1);
    pA[k] = x16 + (size_t)tok[e*TT+ar]*HH + csw;
    int p = 2*k + (r>>5), mat = (r>>4)&1;
    pB[k] = w13 + (size_t)e*(2*DD)*HH + (size_t)(mat*DD + n0 + p*16 + (r&15))*HH + csw;
  }

  f32x4 acc[8][4];
  #pragma unroll
  for (int i=0;i<8;i++)
    #pragma unroll
    for (int j=0;j<4;j++) acc[i][j] = {0.f,0.f,0.f,0.f};
  bf16x8 a[4][2], b0[2][2], b1[2][2];

  PROLOGUE
  KLOOP

  #pragma unroll
  for (int mf=0;mf<8;mf++){
    int rb = ((mf<4)? wm*64 + mf*16 : 128 + wm*64 + (mf-4)*16) + klane*4;
    #pragma unroll
    for (int q=0;q<4;q++){
      int gm = m0 + rb + q;
      if (gm < ce){
        size_t hrow = (size_t)(oe+gm)*DD;
        #pragma unroll
        for (int pp=0;pp<2;pp++){
          float g = acc[mf][2*pp][q], u = acc[mf][2*pp+1][q];
          float t2 = 1.5957691216057308f*(g + 0.044715f*g*g*g);  // 2*sqrt(2/pi)*(...)
          float sg = 1.f/(1.f+__expf(-t2));                      // 0.5*(1+tanh(t)) = sigmoid(2t)
          hbuf[hrow + n0 + pp*64 + wn*16 + frow] = f2bf(g*u*sg);
        }
      }
    }
  }
}

// ---------------- GEMM2: 256 rows x 256 out-cols, weighted atomic scatter ----------------
__global__ __launch_bounds__(512,2) void ffn2_kernel(
    const ushort* __restrict__ hbuf, const ushort* __restrict__ w2,
    const int* __restrict__ cnt, const int* __restrict__ off,
    const int* __restrict__ tok, const float* __restrict__ wgt,
    float* __restrict__ out)
{
  int e  = blockIdx.z;
  int ce = cnt[e];
  int m0 = blockIdx.y<<8;
  if (m0 >= ce) return;
  int n0 = blockIdx.x<<8;

  __shared__ ushort ldsA[2][256*64];
  __shared__ ushort ldsB[2][256*64];

  int tid = threadIdx.x, wid = tid>>6, lane = tid&63;
  int wm = wid>>2, wn = wid&3;
  int frow = lane&15, klane = lane>>4;
  int c0 = ((klane  ) ^ (frow&7))<<3;
  int c1 = ((klane+4) ^ (frow&7))<<3;

  int r   = wid*8 + (lane>>3);
  int csw = ((lane&7) ^ (lane>>3))<<3;

  const ushort* pA[4]; const ushort* pB[4];
  int oe = off[e];
  #pragma unroll
  for (int k=0;k<4;k++){
    int R  = k*64 + r;
    int ar = oe + min(m0+R, ce-1);
    pA[k] = hbuf + (size_t)ar*DD + csw;
    pB[k] = w2 + (size_t)e*HH*DD + (size_t)(n0 + R)*DD + csw;
  }

  f32x4 acc[8][4];
  #pragma unroll
  for (int i=0;i<8;i++)
    #pragma unroll
    for (int j=0;j<4;j++) acc[i][j] = {0.f,0.f,0.f,0.f};
  bf16x8 a[4][2], b0[2][2], b1[2][2];

  PROLOGUE
  KLOOP

  #pragma unroll
  for (int mf=0;mf<8;mf++){
    int rb = ((mf<4)? wm*64 + mf*16 : 128 + wm*64 + (mf-4)*16) + klane*4;
    #pragma unroll
    for (int q=0;q<4;q++){
      int gm = m0 + rb + q;
      if (gm < ce){
        int   tk = tok[e*TT+gm];
        float w  = wgt[e*TT+gm];
        float* orow = out + (size_t)tk*HH + n0;
        #pragma unroll
        for (int nf=0;nf<4;nf++){
          int col = (nf>>1)*128 + wn*32 + (nf&1)*16 + frow;
          atomicAdd(orow + col, w*acc[mf][nf][q]);  // 2 commutative adds/element
        }
      }
    }
  }
}

extern "C" void kernel_launch(void* const* d_in, const int* in_sizes, int n_in,
                              void* d_out, int out_size, void* d_ws, size_t ws_size,
                              hipStream_t stream)
{
  const float* x    = (const float*)d_in[0];
  const float* rsc  = (const float*)d_in[1];
  const float* pes  = (const float*)d_in[2];
  const float* rw   = (const float*)d_in[3];
  const float* w13f = (const float*)d_in[4];
  const float* w2f  = (const float*)d_in[5];
  float* out = (float*)d_out;

  char* ws = (char*)d_ws;
  size_t o_x16 = 0;
  size_t o_w13 = o_x16 + (size_t)TT*HH*2;
  size_t o_w2  = o_w13 + (size_t)EE*2*DD*HH*2;
  size_t o_h   = o_w2  + (size_t)EE*HH*DD*2;
  size_t o_cnt = o_h   + (size_t)2*TT*DD*2;
  size_t o_off = o_cnt + 128;
  size_t o_tok = o_off + 128;
  size_t o_wgt = o_tok + (size_t)EE*TT*4;
  size_t need  = o_wgt + (size_t)EE*TT*4;

  hipMemsetAsync(d_out, 0, (size_t)TT*HH*sizeof(float), stream);
  if (ws_size < need) return;

  ushort* x16 = (ushort*)(ws + o_x16);
  ushort* w13 = (ushort*)(ws + o_w13);
  ushort* w2  = (ushort*)(ws + o_w2);
  ushort* hbuf= (ushort*)(ws + o_h);
  int*   cnt  = (int*)(ws + o_cnt);
  int*   off  = (int*)(ws + o_off);
  int*   tok  = (int*)(ws + o_tok);
  float* wgt  = (float*)(ws + o_wgt);

  hipMemsetAsync(cnt, 0, EE*sizeof(int), stream);
  cvt_kernel<<<4096,256,0,stream>>>(w13f, w13, (size_t)EE*2*DD*HH);
  cvt_kernel<<<2048,256,0,stream>>>(w2f,  w2,  (size_t)EE*HH*DD);
  router_kernel<<<TT,256,0,stream>>>(x, rsc, pes, rw, x16, cnt, tok, wgt);
  scan_kernel<<<1,64,0,stream>>>(cnt, off);
  dim3 g1(DD/128, TT/256, EE);   // 16 x 32 x 8
  ffn1_kernel<<<g1,512,0,stream>>>(x16, w13, cnt, off, tok, hbuf);
  dim3 g2(HH/256, TT/256, EE);   // 8 x 32 x 8
  ffn2_kernel<<<g2,512,0,stream>>>(hbuf, w2, cnt, off, tok, wgt, out);
}